// Round 1
// baseline (723.183 us; speedup 1.0000x reference)
//
#include <hip/hip_runtime.h>
#include <hip/hip_bf16.h>

// Problem constants
#define B_   256
#define L_   64
#define DT_  768
#define DH_  128
#define AL_  48
#define DTE_ 64
#define H_   8
#define NL_  3
#define DFF_ 512

// ---------------- Generic tiled fp32 GEMM: C = A(MxK) @ W(KxN) (+bias)(+relu)
#define BM 64
#define BN 64
#define BKK 16
__global__ __launch_bounds__(256) void gemm_kernel(
    const float* __restrict__ A, const float* __restrict__ W,
    const float* __restrict__ bias, float* __restrict__ C,
    int M, int N, int K, int do_relu)
{
    __shared__ float As[BKK][BM + 1];
    __shared__ float Bs[BKK][BN + 1];
    int tid = threadIdx.x;
    int bm = blockIdx.x * BM;
    int bn = blockIdx.y * BN;
    int tx = tid & 15, ty = tid >> 4;
    float acc[4][4] = {};
    for (int k0 = 0; k0 < K; k0 += BKK) {
        {
            int k = tid & 15;
            int m0 = tid >> 4;
            #pragma unroll
            for (int i = 0; i < 4; ++i) {
                int m = m0 + 16 * i;
                As[k][m] = A[(size_t)(bm + m) * K + k0 + k];
            }
        }
        {
            int n = tid & 63;
            int kbase = (tid >> 6) * 4;
            #pragma unroll
            for (int i = 0; i < 4; ++i) {
                int k = kbase + i;
                Bs[k][n] = W[(size_t)(k0 + k) * N + bn + n];
            }
        }
        __syncthreads();
        #pragma unroll
        for (int k = 0; k < BKK; ++k) {
            float a[4], b[4];
            #pragma unroll
            for (int i = 0; i < 4; ++i) a[i] = As[k][ty * 4 + i];
            #pragma unroll
            for (int j = 0; j < 4; ++j) b[j] = Bs[k][tx * 4 + j];
            #pragma unroll
            for (int i = 0; i < 4; ++i)
                #pragma unroll
                for (int j = 0; j < 4; ++j)
                    acc[i][j] = fmaf(a[i], b[j], acc[i][j]);
        }
        __syncthreads();
    }
    #pragma unroll
    for (int i = 0; i < 4; ++i) {
        int row = bm + ty * 4 + i;
        #pragma unroll
        for (int j = 0; j < 4; ++j) {
            int col = bn + tx * 4 + j;
            float v = acc[i][j];
            if (bias) v += bias[col];
            if (do_relu) v = fmaxf(v, 0.f);
            C[(size_t)row * N + col] = v;
        }
    }
}

// ---------------- q_all = time_embed(arange(48)) @ wq   (48 x 64)
__global__ __launch_bounds__(256) void compute_q_kernel(
    const float* __restrict__ te_w, const float* __restrict__ te_b,
    const float* __restrict__ wq, float* __restrict__ q_all)
{
    __shared__ float qte[AL_ * DTE_];
    int tid = threadIdx.x;
    for (int idx = tid; idx < AL_ * DTE_; idx += 256) {
        int a = idx >> 6, j = idx & 63;
        float lin = fmaf((float)a, te_w[j], te_b[j]);
        qte[idx] = (j == 0) ? lin : sinf(lin);
    }
    __syncthreads();
    for (int idx = tid; idx < AL_ * DTE_; idx += 256) {
        int a = idx >> 6, j2 = idx & 63;
        float s = 0.f;
        for (int j = 0; j < DTE_; ++j) s = fmaf(qte[a * 64 + j], wq[j * 64 + j2], s);
        q_all[idx] = s;
    }
}

// ---------------- First (irregular-time) attention, fused per batch element.
// x[b,a,:] = (1/H * sum_h softmax_h(q[a,h,:].k[b,l,h,:]/sqrt(8), mask)) @ note_emb[b]
__global__ __launch_bounds__(256) void first_attn_kernel(
    const float* __restrict__ note_times, const int* __restrict__ note_counts,
    const float* __restrict__ te_w, const float* __restrict__ te_b,
    const float* __restrict__ wk, const float* __restrict__ q_all,
    const float* __restrict__ note_emb, float* __restrict__ x_out)
{
    __shared__ float kte[L_ * DTE_];   // 4096 floats; first 3072 reused as sc
    __shared__ float kk[L_ * DTE_];    // 4096
    __shared__ float qs[AL_ * DTE_];   // 3072
    __shared__ float abar[AL_ * L_];   // 3072
    int b = blockIdx.x;
    int tid = threadIdx.x;
    int nc = note_counts[b];

    for (int idx = tid; idx < L_ * DTE_; idx += 256) {
        int l = idx >> 6, j = idx & 63;
        float t = note_times[b * L_ + l];
        float lin = fmaf(t, te_w[j], te_b[j]);
        kte[idx] = (j == 0) ? lin : sinf(lin);
    }
    for (int idx = tid; idx < AL_ * DTE_; idx += 256) qs[idx] = q_all[idx];
    for (int idx = tid; idx < AL_ * L_; idx += 256) abar[idx] = 0.f;
    __syncthreads();

    // kk = kte @ wk   (64 x 64)
    for (int idx = tid; idx < L_ * DTE_; idx += 256) {
        int l = idx >> 6, d = idx & 63;
        float s = 0.f;
        for (int j = 0; j < DTE_; ++j) s = fmaf(kte[l * 64 + j], wk[j * 64 + d], s);
        kk[idx] = s;
    }
    __syncthreads();

    float* sc = kte;  // alias (kte dead now), 48*64
    const float scale = 0.35355339059327373f; // 1/sqrt(8)
    for (int h = 0; h < H_; ++h) {
        for (int idx = tid; idx < AL_ * L_; idx += 256) {
            int a = idx >> 6, l = idx & 63;
            float s = 0.f;
            #pragma unroll
            for (int d = 0; d < 8; ++d)
                s = fmaf(qs[a * 64 + h * 8 + d], kk[l * 64 + h * 8 + d], s);
            sc[idx] = (l < nc) ? s * scale : -1e9f;
        }
        __syncthreads();
        if (tid < AL_) {
            float m = -1e30f;
            for (int l = 0; l < L_; ++l) m = fmaxf(m, sc[tid * 64 + l]);
            float sum = 0.f;
            for (int l = 0; l < L_; ++l) {
                float e = expf(sc[tid * 64 + l] - m);
                sc[tid * 64 + l] = e; sum += e;
            }
            float inv = 0.125f / sum;  // fold mean over heads
            for (int l = 0; l < L_; ++l) abar[tid * 64 + l] += sc[tid * 64 + l] * inv;
        }
        __syncthreads();
    }

    for (int idx = tid; idx < AL_ * DH_; idx += 256) {
        int a = idx >> 7, f = idx & 127;
        float s = 0.f;
        for (int l = 0; l < L_; ++l)
            s = fmaf(abar[a * 64 + l], note_emb[((size_t)b * L_ + l) * DH_ + f], s);
        x_out[((size_t)b * AL_ + a) * DH_ + f] = (nc > 0) ? s : 0.f;
    }
}

// ---------------- Transformer self-attention: one block per (b, h)
__global__ __launch_bounds__(256) void attn2_kernel(
    const float* __restrict__ q, const float* __restrict__ k,
    const float* __restrict__ v, float* __restrict__ o)
{
    __shared__ float qh[AL_ * 16], kh[AL_ * 16], vh[AL_ * 16];
    __shared__ float s[AL_ * AL_];
    int bid = blockIdx.x;
    int b = bid >> 3, h = bid & 7;
    int tid = threadIdx.x;
    size_t base = (size_t)b * AL_ * DH_ + h * 16;
    for (int idx = tid; idx < AL_ * 16; idx += 256) {
        int a = idx >> 4, d = idx & 15;
        qh[idx] = q[base + (size_t)a * DH_ + d];
        kh[idx] = k[base + (size_t)a * DH_ + d];
        vh[idx] = v[base + (size_t)a * DH_ + d];
    }
    __syncthreads();
    for (int idx = tid; idx < AL_ * AL_; idx += 256) {
        int a = idx / AL_, kx = idx - a * AL_;
        float acc = 0.f;
        #pragma unroll
        for (int d = 0; d < 16; ++d) acc = fmaf(qh[a * 16 + d], kh[kx * 16 + d], acc);
        s[idx] = acc * 0.25f;  // 1/sqrt(16)
    }
    __syncthreads();
    if (tid < AL_) {
        float m = -1e30f;
        for (int j = 0; j < AL_; ++j) m = fmaxf(m, s[tid * AL_ + j]);
        float sum = 0.f;
        for (int j = 0; j < AL_; ++j) {
            float e = expf(s[tid * AL_ + j] - m);
            s[tid * AL_ + j] = e; sum += e;
        }
        float inv = 1.f / sum;
        for (int j = 0; j < AL_; ++j) s[tid * AL_ + j] *= inv;
    }
    __syncthreads();
    for (int idx = tid; idx < AL_ * 16; idx += 256) {
        int a = idx >> 4, d = idx & 15;
        float acc = 0.f;
        for (int j = 0; j < AL_; ++j) acc = fmaf(s[a * AL_ + j], vh[j * 16 + d], acc);
        o[base + (size_t)a * DH_ + d] = acc;
    }
}

// ---------------- x = LN(x + r) * g + b  (rows of 128, one wave per row)
__global__ __launch_bounds__(256) void add_ln_kernel(
    float* __restrict__ x, const float* __restrict__ r,
    const float* __restrict__ g, const float* __restrict__ bta, int rows)
{
    int row = blockIdx.x * 4 + (threadIdx.x >> 6);
    int lane = threadIdx.x & 63;
    if (row >= rows) return;
    size_t off = (size_t)row * DH_;
    float v0 = x[off + lane] + r[off + lane];
    float v1 = x[off + 64 + lane] + r[off + 64 + lane];
    float sum = v0 + v1;
    float sq = v0 * v0 + v1 * v1;
    #pragma unroll
    for (int d = 32; d >= 1; d >>= 1) {
        sum += __shfl_xor(sum, d);
        sq  += __shfl_xor(sq, d);
    }
    float mu = sum * (1.f / 128.f);
    float var = sq * (1.f / 128.f) - mu * mu;
    float rs = rsqrtf(var + 1e-5f);
    x[off + lane]      = (v0 - mu) * rs * g[lane] + bta[lane];
    x[off + 64 + lane] = (v1 - mu) * rs * g[lane + 64] + bta[lane + 64];
}

// ---------------- Classifier head: one wave per batch element
__global__ __launch_bounds__(64) void head_kernel(
    const float* __restrict__ x, const float* __restrict__ w1,
    const float* __restrict__ b1, const float* __restrict__ w2,
    const float* __restrict__ b2, float* __restrict__ out)
{
    int b = blockIdx.x;
    int j = threadIdx.x; // 0..63
    const float* xr = x + ((size_t)b * AL_ + (AL_ - 1)) * DH_;
    float hj = b1[j];
    for (int d = 0; d < DH_; ++d) hj = fmaf(xr[d], w1[d * 64 + j], hj);
    hj = fmaxf(hj, 0.f);
    float acc = hj * w2[j];
    #pragma unroll
    for (int d = 32; d >= 1; d >>= 1) acc += __shfl_xor(acc, d);
    if (j == 0) out[b] = acc + b2[0];
}

// ---------------- Launch
extern "C" void kernel_launch(void* const* d_in, const int* in_sizes, int n_in,
                              void* d_out, int out_size, void* d_ws, size_t ws_size,
                              hipStream_t stream) {
    (void)in_sizes; (void)n_in; (void)out_size; (void)ws_size;
    const float* cls_emb    = (const float*)d_in[0];
    const float* note_times = (const float*)d_in[1];
    const int*   note_counts= (const int*)d_in[2];
    const float* proj_w     = (const float*)d_in[3];
    const float* proj_b     = (const float*)d_in[4];
    const float* te_w       = (const float*)d_in[5];
    const float* te_b       = (const float*)d_in[6];
    const float* wq         = (const float*)d_in[7];
    const float* wk         = (const float*)d_in[8];
    const float* tf_wq      = (const float*)d_in[9];
    const float* tf_wk      = (const float*)d_in[10];
    const float* tf_wv      = (const float*)d_in[11];
    const float* tf_wo      = (const float*)d_in[12];
    const float* tf_ln1_g   = (const float*)d_in[13];
    const float* tf_ln1_b   = (const float*)d_in[14];
    const float* tf_w1      = (const float*)d_in[15];
    const float* tf_b1      = (const float*)d_in[16];
    const float* tf_w2      = (const float*)d_in[17];
    const float* tf_b2      = (const float*)d_in[18];
    const float* tf_ln2_g   = (const float*)d_in[19];
    const float* tf_ln2_b   = (const float*)d_in[20];
    const float* cls_w1     = (const float*)d_in[21];
    const float* cls_b1     = (const float*)d_in[22];
    const float* cls_w2     = (const float*)d_in[23];
    const float* cls_b2     = (const float*)d_in[24];
    float* out = (float*)d_out;
    float* ws = (float*)d_ws;

    // workspace layout (floats)
    float* note_emb = ws + 0;              // 2,097,152
    float* x        = ws + 2097152;        // 1,572,864
    float* qb       = ws + 3670016;        // 1,572,864
    float* kb       = ws + 5242880;        // 1,572,864
    float* vb       = ws + 6815744;        // 1,572,864
    float* cbuf     = ws + 8388608;        // 6,291,456 (o_pre / ffn hidden)
    float* dbuf     = ws + 14680064;       // 1,572,864 (o2 / ffn out)
    float* q_all    = ws + 16252928;       // 3,072

    const int Mx = B_ * AL_; // 12288

    // note_emb = cls_emb @ proj_w + proj_b
    gemm_kernel<<<dim3((B_ * L_) / BM, DH_ / BN), 256, 0, stream>>>(
        cls_emb, proj_w, proj_b, note_emb, B_ * L_, DH_, DT_, 0);

    compute_q_kernel<<<1, 256, 0, stream>>>(te_w, te_b, wq, q_all);

    first_attn_kernel<<<B_, 256, 0, stream>>>(
        note_times, note_counts, te_w, te_b, wk, q_all, note_emb, x);

    for (int i = 0; i < NL_; ++i) {
        const float* wqi = tf_wq + (size_t)i * DH_ * DH_;
        const float* wki = tf_wk + (size_t)i * DH_ * DH_;
        const float* wvi = tf_wv + (size_t)i * DH_ * DH_;
        const float* woi = tf_wo + (size_t)i * DH_ * DH_;
        gemm_kernel<<<dim3(Mx / BM, DH_ / BN), 256, 0, stream>>>(x, wqi, nullptr, qb, Mx, DH_, DH_, 0);
        gemm_kernel<<<dim3(Mx / BM, DH_ / BN), 256, 0, stream>>>(x, wki, nullptr, kb, Mx, DH_, DH_, 0);
        gemm_kernel<<<dim3(Mx / BM, DH_ / BN), 256, 0, stream>>>(x, wvi, nullptr, vb, Mx, DH_, DH_, 0);
        attn2_kernel<<<B_ * H_, 256, 0, stream>>>(qb, kb, vb, cbuf);
        gemm_kernel<<<dim3(Mx / BM, DH_ / BN), 256, 0, stream>>>(cbuf, woi, nullptr, dbuf, Mx, DH_, DH_, 0);
        add_ln_kernel<<<Mx / 4, 256, 0, stream>>>(x, dbuf, tf_ln1_g + i * DH_, tf_ln1_b + i * DH_, Mx);
        gemm_kernel<<<dim3(Mx / BM, DFF_ / BN), 256, 0, stream>>>(
            x, tf_w1 + (size_t)i * DH_ * DFF_, tf_b1 + i * DFF_, cbuf, Mx, DFF_, DH_, 1);
        gemm_kernel<<<dim3(Mx / BM, DH_ / BN), 256, 0, stream>>>(
            cbuf, tf_w2 + (size_t)i * DFF_ * DH_, tf_b2 + i * DH_, dbuf, Mx, DH_, DFF_, 0);
        add_ln_kernel<<<Mx / 4, 256, 0, stream>>>(x, dbuf, tf_ln2_g + i * DH_, tf_ln2_b + i * DH_, Mx);
    }

    head_kernel<<<B_, 64, 0, stream>>>(x, cls_w1, cls_b1, cls_w2, cls_b2, out);
}

// Round 2
// 414.992 us; speedup vs baseline: 1.7426x; 1.7426x over previous
//
#include <hip/hip_runtime.h>
#include <hip/hip_bf16.h>

// Problem constants
#define B_   256
#define L_   64
#define DT_  768
#define DH_  128
#define AL_  48
#define DTE_ 64
#define H_   8
#define NL_  3
#define DFF_ 512

typedef __attribute__((ext_vector_type(4))) float f32x4;
typedef __attribute__((ext_vector_type(4))) unsigned int u32x4;
typedef __attribute__((ext_vector_type(2))) unsigned int u32x2;
typedef __attribute__((ext_vector_type(8))) short short8;

__device__ inline unsigned short f2bf(float f) {
    union { float f; unsigned u; } v; v.f = f;
    unsigned r = (v.u + 0x7FFFu + ((v.u >> 16) & 1u)) >> 16;
    return (unsigned short)r;
}
__device__ inline unsigned f2bf2(float a, float b) {
    return (unsigned)f2bf(a) | ((unsigned)f2bf(b) << 16);
}

// ================= Weight prep: fp32 [K][N] -> bf16 Wt [N][K] =================
struct TEnt { const float* src; int dstOff; int K; int N; int tile0; };
struct TTab { TEnt e[19]; };

__global__ __launch_bounds__(256) void prep_weights_kernel(TTab tab, unsigned short* __restrict__ wt)
{
    __shared__ unsigned short lds[64][72];
    int ei = 0;
    #pragma unroll
    for (int j = 1; j < 19; ++j) if ((int)blockIdx.x >= tab.e[j].tile0) ei = j;
    TEnt e = tab.e[ei];
    int t = blockIdx.x - e.tile0;
    int tilesK = e.K >> 6;
    int tk = t % tilesK, tn = t / tilesK;
    int tid = threadIdx.x;
    #pragma unroll
    for (int p = 0; p < 16; ++p) {
        int kk = p * 4 + (tid >> 6);
        int n = tid & 63;
        float v = e.src[(size_t)(tk * 64 + kk) * e.N + tn * 64 + n];
        lds[n][kk] = f2bf(v);
    }
    __syncthreads();
    #pragma unroll
    for (int p = 0; p < 2; ++p) {
        int c = p * 256 + tid;
        int n = c >> 3, q = c & 7;
        u32x4 v = *(const u32x4*)(&lds[n][q * 8]);
        *(u32x4*)(&wt[(size_t)e.dstOff + (size_t)(tn * 64 + n) * e.K + tk * 64 + q * 8]) = v;
    }
}

// ================= bf16 MFMA GEMM: C = A(fp32 MxK) @ Wt^T (Wt bf16 [N][K]) ====
// Tile: BM_ x 128, BK=64. 4 waves, wave grid 2x2, wave tile (BM_/2) x 64.
template<int BM_>
__global__ __launch_bounds__(256) void gemm_bf16_kernel(
    const float* __restrict__ A, const unsigned short* __restrict__ Wt,
    const float* __restrict__ bias, float* __restrict__ C,
    int M, int N, int K, int relu)
{
    constexpr int MF = BM_ / 32;           // m-frags per wave
    __shared__ unsigned short As[BM_ * 64];
    __shared__ unsigned short Bs[128 * 64];
    int tid = threadIdx.x;
    int bm = blockIdx.x * BM_;
    int bn = blockIdx.y * 128;
    int wave = tid >> 6, lane = tid & 63;
    int wm = wave >> 1, wn = wave & 1;
    int g = lane >> 4, r16 = lane & 15;

    f32x4 acc[MF][4] = {};

    for (int k0 = 0; k0 < K; k0 += 64) {
        // ---- stage A (fp32 -> bf16), BM_ x 64
        #pragma unroll
        for (int p = 0; p < BM_ / 16; ++p) {
            int row = p * 16 + (tid >> 4);
            int c4 = tid & 15;
            f32x4 v = *(const f32x4*)(&A[(size_t)(bm + row) * K + k0 + c4 * 4]);
            u32x2 w;
            w[0] = f2bf2(v[0], v[1]);
            w[1] = f2bf2(v[2], v[3]);
            int idx = row * 64 + ((c4 * 4) ^ ((row & 7) << 3));
            *(u32x2*)(&As[idx]) = w;
        }
        // ---- stage B (bf16 copy), 128 x 64
        #pragma unroll
        for (int p = 0; p < 4; ++p) {
            int c = p * 256 + tid;
            int n = c >> 3, q = c & 7;
            u32x4 v = *(const u32x4*)(&Wt[(size_t)(bn + n) * K + k0 + q * 8]);
            int idx = n * 64 + ((q * 8) ^ ((n & 7) << 3));
            *(u32x4*)(&Bs[idx]) = v;
        }
        __syncthreads();
        // ---- compute: 2 MFMA k-steps of 32
        #pragma unroll
        for (int kk = 0; kk < 2; ++kk) {
            short8 af[MF], bf[4];
            int co = kk * 32 + g * 8;
            #pragma unroll
            for (int mi = 0; mi < MF; ++mi) {
                int row = wm * (BM_ / 2) + mi * 16 + r16;
                af[mi] = *(const short8*)(&As[row * 64 + (co ^ ((row & 7) << 3))]);
            }
            #pragma unroll
            for (int ni = 0; ni < 4; ++ni) {
                int row = wn * 64 + ni * 16 + r16;
                bf[ni] = *(const short8*)(&Bs[row * 64 + (co ^ ((row & 7) << 3))]);
            }
            #pragma unroll
            for (int mi = 0; mi < MF; ++mi)
                #pragma unroll
                for (int ni = 0; ni < 4; ++ni)
                    acc[mi][ni] = __builtin_amdgcn_mfma_f32_16x16x32_bf16(
                        af[mi], bf[ni], acc[mi][ni], 0, 0, 0);
        }
        __syncthreads();
    }
    // ---- epilogue
    #pragma unroll
    for (int mi = 0; mi < MF; ++mi) {
        #pragma unroll
        for (int ni = 0; ni < 4; ++ni) {
            int col = bn + wn * 64 + ni * 16 + r16;
            float bv = bias ? bias[col] : 0.f;
            #pragma unroll
            for (int r = 0; r < 4; ++r) {
                int row = bm + wm * (BM_ / 2) + mi * 16 + g * 4 + r;
                float v = acc[mi][ni][r] + bv;
                if (relu) v = fmaxf(v, 0.f);
                C[(size_t)row * N + col] = v;
            }
        }
    }
}

// ================= q_all = time_embed(arange(48)) @ wq  (48 x 64) =============
__global__ __launch_bounds__(256) void compute_q_kernel(
    const float* __restrict__ te_w, const float* __restrict__ te_b,
    const float* __restrict__ wq, float* __restrict__ q_all)
{
    __shared__ float qte[AL_ * DTE_];
    int tid = threadIdx.x;
    for (int idx = tid; idx < AL_ * DTE_; idx += 256) {
        int a = idx >> 6, j = idx & 63;
        float lin = fmaf((float)a, te_w[j], te_b[j]);
        qte[idx] = (j == 0) ? lin : sinf(lin);
    }
    __syncthreads();
    for (int idx = tid; idx < AL_ * DTE_; idx += 256) {
        int a = idx >> 6, j2 = idx & 63;
        float s = 0.f;
        for (int j = 0; j < DTE_; ++j) s = fmaf(qte[a * 64 + j], wq[j * 64 + j2], s);
        q_all[idx] = s;
    }
}

// ================= First (irregular-time) attention, fused per batch ==========
__global__ __launch_bounds__(256) void first_attn_kernel(
    const float* __restrict__ note_times, const int* __restrict__ note_counts,
    const float* __restrict__ te_w, const float* __restrict__ te_b,
    const float* __restrict__ wk, const float* __restrict__ q_all,
    const float* __restrict__ note_emb, float* __restrict__ x_out)
{
    __shared__ float kte[L_ * DTE_];
    __shared__ float kk[L_ * DTE_];
    __shared__ float qs[AL_ * DTE_];
    __shared__ float abar[AL_ * L_];
    int b = blockIdx.x;
    int tid = threadIdx.x;
    int nc = note_counts[b];

    for (int idx = tid; idx < L_ * DTE_; idx += 256) {
        int l = idx >> 6, j = idx & 63;
        float t = note_times[b * L_ + l];
        float lin = fmaf(t, te_w[j], te_b[j]);
        kte[idx] = (j == 0) ? lin : sinf(lin);
    }
    for (int idx = tid; idx < AL_ * DTE_; idx += 256) qs[idx] = q_all[idx];
    for (int idx = tid; idx < AL_ * L_; idx += 256) abar[idx] = 0.f;
    __syncthreads();

    for (int idx = tid; idx < L_ * DTE_; idx += 256) {
        int l = idx >> 6, d = idx & 63;
        float s = 0.f;
        for (int j = 0; j < DTE_; ++j) s = fmaf(kte[l * 64 + j], wk[j * 64 + d], s);
        kk[idx] = s;
    }
    __syncthreads();

    float* sc = kte;
    const float scale = 0.35355339059327373f;
    for (int h = 0; h < H_; ++h) {
        for (int idx = tid; idx < AL_ * L_; idx += 256) {
            int a = idx >> 6, l = idx & 63;
            float s = 0.f;
            #pragma unroll
            for (int d = 0; d < 8; ++d)
                s = fmaf(qs[a * 64 + h * 8 + d], kk[l * 64 + h * 8 + d], s);
            sc[idx] = (l < nc) ? s * scale : -1e9f;
        }
        __syncthreads();
        if (tid < AL_) {
            float m = -1e30f;
            for (int l = 0; l < L_; ++l) m = fmaxf(m, sc[tid * 64 + l]);
            float sum = 0.f;
            for (int l = 0; l < L_; ++l) {
                float e = expf(sc[tid * 64 + l] - m);
                sc[tid * 64 + l] = e; sum += e;
            }
            float inv = 0.125f / sum;
            for (int l = 0; l < L_; ++l) abar[tid * 64 + l] += sc[tid * 64 + l] * inv;
        }
        __syncthreads();
    }

    for (int idx = tid; idx < AL_ * DH_; idx += 256) {
        int a = idx >> 7, f = idx & 127;
        float s = 0.f;
        for (int l = 0; l < L_; ++l)
            s = fmaf(abar[a * 64 + l], note_emb[((size_t)b * L_ + l) * DH_ + f], s);
        x_out[((size_t)b * AL_ + a) * DH_ + f] = (nc > 0) ? s : 0.f;
    }
}

// ================= Transformer self-attention: block per (b,h), qkv packed ====
__global__ __launch_bounds__(256) void attn2_kernel(
    const float* __restrict__ qkv, float* __restrict__ o)
{
    __shared__ float qh[AL_ * 16], kh[AL_ * 16], vh[AL_ * 16];
    __shared__ float s[AL_ * AL_];
    int bid = blockIdx.x;
    int b = bid >> 3, h = bid & 7;
    int tid = threadIdx.x;
    const float* base = qkv + (size_t)b * AL_ * 384 + h * 16;
    for (int idx = tid; idx < AL_ * 16; idx += 256) {
        int a = idx >> 4, d = idx & 15;
        qh[idx] = base[(size_t)a * 384 + d];
        kh[idx] = base[(size_t)a * 384 + 128 + d];
        vh[idx] = base[(size_t)a * 384 + 256 + d];
    }
    __syncthreads();
    for (int idx = tid; idx < AL_ * AL_; idx += 256) {
        int a = idx / AL_, kx = idx - a * AL_;
        float acc = 0.f;
        #pragma unroll
        for (int d = 0; d < 16; ++d) acc = fmaf(qh[a * 16 + d], kh[kx * 16 + d], acc);
        s[idx] = acc * 0.25f;
    }
    __syncthreads();
    if (tid < AL_) {
        float m = -1e30f;
        for (int j = 0; j < AL_; ++j) m = fmaxf(m, s[tid * AL_ + j]);
        float sum = 0.f;
        for (int j = 0; j < AL_; ++j) {
            float e = expf(s[tid * AL_ + j] - m);
            s[tid * AL_ + j] = e; sum += e;
        }
        float inv = 1.f / sum;
        for (int j = 0; j < AL_; ++j) s[tid * AL_ + j] *= inv;
    }
    __syncthreads();
    for (int idx = tid; idx < AL_ * 16; idx += 256) {
        int a = idx >> 4, d = idx & 15;
        float acc = 0.f;
        for (int j = 0; j < AL_; ++j) acc = fmaf(s[a * AL_ + j], vh[j * 16 + d], acc);
        o[((size_t)b * AL_ + a) * DH_ + h * 16 + d] = acc;
    }
}

// ================= x = LN(x + r) * g + b ======================================
__global__ __launch_bounds__(256) void add_ln_kernel(
    float* __restrict__ x, const float* __restrict__ r,
    const float* __restrict__ g, const float* __restrict__ bta, int rows)
{
    int row = blockIdx.x * 4 + (threadIdx.x >> 6);
    int lane = threadIdx.x & 63;
    if (row >= rows) return;
    size_t off = (size_t)row * DH_;
    float v0 = x[off + lane] + r[off + lane];
    float v1 = x[off + 64 + lane] + r[off + 64 + lane];
    float sum = v0 + v1;
    float sq = v0 * v0 + v1 * v1;
    #pragma unroll
    for (int d = 32; d >= 1; d >>= 1) {
        sum += __shfl_xor(sum, d);
        sq  += __shfl_xor(sq, d);
    }
    float mu = sum * (1.f / 128.f);
    float var = sq * (1.f / 128.f) - mu * mu;
    float rs = rsqrtf(var + 1e-5f);
    x[off + lane]      = (v0 - mu) * rs * g[lane] + bta[lane];
    x[off + 64 + lane] = (v1 - mu) * rs * g[lane + 64] + bta[lane + 64];
}

// ================= Classifier head ============================================
__global__ __launch_bounds__(64) void head_kernel(
    const float* __restrict__ x, const float* __restrict__ w1,
    const float* __restrict__ b1, const float* __restrict__ w2,
    const float* __restrict__ b2, float* __restrict__ out)
{
    int b = blockIdx.x;
    int j = threadIdx.x;
    const float* xr = x + ((size_t)b * AL_ + (AL_ - 1)) * DH_;
    float hj = b1[j];
    for (int d = 0; d < DH_; ++d) hj = fmaf(xr[d], w1[d * 64 + j], hj);
    hj = fmaxf(hj, 0.f);
    float acc = hj * w2[j];
    #pragma unroll
    for (int d = 32; d >= 1; d >>= 1) acc += __shfl_xor(acc, d);
    if (j == 0) out[b] = acc + b2[0];
}

// ================= Launch =====================================================
extern "C" void kernel_launch(void* const* d_in, const int* in_sizes, int n_in,
                              void* d_out, int out_size, void* d_ws, size_t ws_size,
                              hipStream_t stream) {
    (void)in_sizes; (void)n_in; (void)out_size; (void)ws_size;
    const float* cls_emb    = (const float*)d_in[0];
    const float* note_times = (const float*)d_in[1];
    const int*   note_counts= (const int*)d_in[2];
    const float* proj_w     = (const float*)d_in[3];
    const float* proj_b     = (const float*)d_in[4];
    const float* te_w       = (const float*)d_in[5];
    const float* te_b       = (const float*)d_in[6];
    const float* wq         = (const float*)d_in[7];
    const float* wk         = (const float*)d_in[8];
    const float* tf_wq      = (const float*)d_in[9];
    const float* tf_wk      = (const float*)d_in[10];
    const float* tf_wv      = (const float*)d_in[11];
    const float* tf_wo      = (const float*)d_in[12];
    const float* tf_ln1_g   = (const float*)d_in[13];
    const float* tf_ln1_b   = (const float*)d_in[14];
    const float* tf_w1      = (const float*)d_in[15];
    const float* tf_b1      = (const float*)d_in[16];
    const float* tf_w2      = (const float*)d_in[17];
    const float* tf_b2      = (const float*)d_in[18];
    const float* tf_ln2_g   = (const float*)d_in[19];
    const float* tf_ln2_b   = (const float*)d_in[20];
    const float* cls_w1     = (const float*)d_in[21];
    const float* cls_b1     = (const float*)d_in[22];
    const float* cls_w2     = (const float*)d_in[23];
    const float* cls_b2     = (const float*)d_in[24];
    float* out = (float*)d_out;
    float* ws = (float*)d_ws;

    // workspace layout (float units)
    float* note_emb = ws + 0;                   // 2,097,152
    float* x        = ws + 2097152;             // 1,572,864
    float* shared_  = ws + 3670016;             // 6,291,456 (qkv [12288][384] / ffn hidden [12288][512])
    float* obuf     = ws + 9961472;             // 1,572,864
    float* dbuf     = ws + 11534336;            // 1,572,864
    float* q_all    = ws + 13107200;            // 3,072
    unsigned short* wt = (unsigned short*)(ws + 13110272); // 688,128 u16

    // ---- weight prep table
    TTab tab;
    int tile = 0, idx = 0;
    auto add = [&](const float* src, int dstOff, int K, int N) {
        tab.e[idx].src = src; tab.e[idx].dstOff = dstOff;
        tab.e[idx].K = K; tab.e[idx].N = N; tab.e[idx].tile0 = tile;
        tile += (K / 64) * (N / 64); ++idx;
    };
    add(proj_w, 0, DT_, DH_);                               // 24 tiles
    int layerBase[NL_];
    for (int i = 0; i < NL_; ++i) {
        int base = 98304 + i * 196608;
        layerBase[i] = base;
        add(tf_wq + (size_t)i * DH_ * DH_, base,           DH_, DH_);
        add(tf_wk + (size_t)i * DH_ * DH_, base + 16384,   DH_, DH_);
        add(tf_wv + (size_t)i * DH_ * DH_, base + 32768,   DH_, DH_);
        add(tf_wo + (size_t)i * DH_ * DH_, base + 49152,   DH_, DH_);
        add(tf_w1 + (size_t)i * DH_ * DFF_, base + 65536,  DH_, DFF_);
        add(tf_w2 + (size_t)i * DFF_ * DH_, base + 131072, DFF_, DH_);
    }
    prep_weights_kernel<<<tile, 256, 0, stream>>>(tab, wt);

    const int Mx = B_ * AL_; // 12288

    // note_emb = cls_emb @ proj_w + proj_b   (16384 x 128, K=768)
    gemm_bf16_kernel<64><<<dim3((B_ * L_) / 64, 1), 256, 0, stream>>>(
        cls_emb, wt, proj_b, note_emb, B_ * L_, DH_, DT_, 0);

    compute_q_kernel<<<1, 256, 0, stream>>>(te_w, te_b, wq, q_all);
    first_attn_kernel<<<B_, 256, 0, stream>>>(
        note_times, note_counts, te_w, te_b, wk, q_all, note_emb, x);

    for (int i = 0; i < NL_; ++i) {
        int base = layerBase[i];
        // qkv = x @ [wq|wk|wv]   (12288 x 384)
        gemm_bf16_kernel<128><<<dim3(Mx / 128, 3), 256, 0, stream>>>(
            x, wt + base, nullptr, shared_, Mx, 384, DH_, 0);
        attn2_kernel<<<B_ * H_, 256, 0, stream>>>(shared_, obuf);
        // dbuf = attn_out @ wo
        gemm_bf16_kernel<64><<<dim3(Mx / 64, 1), 256, 0, stream>>>(
            obuf, wt + base + 49152, nullptr, dbuf, Mx, DH_, DH_, 0);
        add_ln_kernel<<<Mx / 4, 256, 0, stream>>>(x, dbuf, tf_ln1_g + i * DH_, tf_ln1_b + i * DH_, Mx);
        // hidden = relu(x @ w1 + b1)  (12288 x 512)
        gemm_bf16_kernel<128><<<dim3(Mx / 128, 4), 256, 0, stream>>>(
            x, wt + base + 65536, tf_b1 + i * DFF_, shared_, Mx, DFF_, DH_, 1);
        // dbuf = hidden @ w2 + b2
        gemm_bf16_kernel<64><<<dim3(Mx / 64, 1), 256, 0, stream>>>(
            shared_, wt + base + 131072, tf_b2 + i * DH_, dbuf, Mx, DH_, DFF_, 0);
        add_ln_kernel<<<Mx / 4, 256, 0, stream>>>(x, dbuf, tf_ln2_g + i * DH_, tf_ln2_b + i * DH_, Mx);
    }

    head_kernel<<<B_, 64, 0, stream>>>(x, cls_w1, cls_b1, cls_w2, cls_b2, out);
}

// Round 3
// 302.428 us; speedup vs baseline: 2.3913x; 1.3722x over previous
//
#include <hip/hip_runtime.h>
#include <hip/hip_bf16.h>

// Problem constants
#define B_   256
#define L_   64
#define DT_  768
#define DH_  128
#define AL_  48
#define DTE_ 64
#define H_   8
#define NL_  3
#define DFF_ 512

typedef __attribute__((ext_vector_type(4))) float f32x4;
typedef __attribute__((ext_vector_type(4))) unsigned int u32x4;
typedef __attribute__((ext_vector_type(2))) unsigned int u32x2;
typedef __attribute__((ext_vector_type(8))) short short8;

__device__ inline unsigned short f2bf(float f) {
    union { float f; unsigned u; } v; v.f = f;
    unsigned r = (v.u + 0x7FFFu + ((v.u >> 16) & 1u)) >> 16;
    return (unsigned short)r;
}
__device__ inline unsigned f2bf2(float a, float b) {
    return (unsigned)f2bf(a) | ((unsigned)f2bf(b) << 16);
}
__device__ inline float bf2f(unsigned short u) {
    union { unsigned u; float f; } v; v.u = ((unsigned)u) << 16; return v.f;
}

// ================= Weight prep: fp32 [K][N] -> bf16 Wt [N][K] =================
struct TEnt { const float* src; int dstOff; int K; int N; int tile0; };
struct TTab { TEnt e[19]; };

__global__ __launch_bounds__(256) void prep_weights_kernel(TTab tab, unsigned short* __restrict__ wt)
{
    __shared__ unsigned short lds[64][72];
    int ei = 0;
    #pragma unroll
    for (int j = 1; j < 19; ++j) if ((int)blockIdx.x >= tab.e[j].tile0) ei = j;
    TEnt e = tab.e[ei];
    int t = blockIdx.x - e.tile0;
    int tilesK = e.K >> 6;
    int tk = t % tilesK, tn = t / tilesK;
    int tid = threadIdx.x;
    #pragma unroll
    for (int p = 0; p < 16; ++p) {
        int kk = p * 4 + (tid >> 6);
        int n = tid & 63;
        float v = e.src[(size_t)(tk * 64 + kk) * e.N + tn * 64 + n];
        lds[n][kk] = f2bf(v);
    }
    __syncthreads();
    #pragma unroll
    for (int p = 0; p < 2; ++p) {
        int c = p * 256 + tid;
        int n = c >> 3, q = c & 7;
        u32x4 v = *(const u32x4*)(&lds[n][q * 8]);
        *(u32x4*)(&wt[(size_t)e.dstOff + (size_t)(tn * 64 + n) * e.K + tk * 64 + q * 8]) = v;
    }
}

// ================= bf16 MFMA GEMM: C = A(MxK) @ Wt^T  ========================
// A fp32 (ABF=0) or bf16 (ABF=1); C fp32 (OUTBF=0) or bf16 (OUTBF=1).
// Tile: BM_ x 128, BK=64. 4 waves, wave grid 2x2, wave tile (BM_/2) x 64.
template<int BM_, int ABF, int OUTBF>
__global__ __launch_bounds__(256) void gemm_bf16_kernel(
    const void* __restrict__ Av, const unsigned short* __restrict__ Wt,
    const float* __restrict__ bias, void* __restrict__ Cv,
    int M, int N, int K, int relu)
{
    constexpr int MF = BM_ / 32;
    __shared__ unsigned short As[BM_ * 64];
    __shared__ unsigned short Bs[128 * 64];
    int tid = threadIdx.x;
    int bm = blockIdx.x * BM_;
    int bn = blockIdx.y * 128;
    int wave = tid >> 6, lane = tid & 63;
    int wm = wave >> 1, wn = wave & 1;
    int g = lane >> 4, r16 = lane & 15;

    f32x4 acc[MF][4] = {};

    for (int k0 = 0; k0 < K; k0 += 64) {
        if constexpr (ABF) {
            const unsigned short* A = (const unsigned short*)Av;
            #pragma unroll
            for (int p = 0; p < MF; ++p) {
                int c = p * 256 + tid;
                int row = c >> 3, c8 = c & 7;
                u32x4 v = *(const u32x4*)(&A[(size_t)(bm + row) * K + k0 + c8 * 8]);
                *(u32x4*)(&As[row * 64 + ((c8 * 8) ^ ((row & 7) << 3))]) = v;
            }
        } else {
            const float* A = (const float*)Av;
            #pragma unroll
            for (int p = 0; p < BM_ / 16; ++p) {
                int row = p * 16 + (tid >> 4);
                int c4 = tid & 15;
                f32x4 v = *(const f32x4*)(&A[(size_t)(bm + row) * K + k0 + c4 * 4]);
                u32x2 w;
                w[0] = f2bf2(v[0], v[1]);
                w[1] = f2bf2(v[2], v[3]);
                *(u32x2*)(&As[row * 64 + ((c4 * 4) ^ ((row & 7) << 3))]) = w;
            }
        }
        #pragma unroll
        for (int p = 0; p < 4; ++p) {
            int c = p * 256 + tid;
            int n = c >> 3, q = c & 7;
            u32x4 v = *(const u32x4*)(&Wt[(size_t)(bn + n) * K + k0 + q * 8]);
            *(u32x4*)(&Bs[n * 64 + ((q * 8) ^ ((n & 7) << 3))]) = v;
        }
        __syncthreads();
        #pragma unroll
        for (int kk = 0; kk < 2; ++kk) {
            short8 af[MF], bf[4];
            int co = kk * 32 + g * 8;
            #pragma unroll
            for (int mi = 0; mi < MF; ++mi) {
                int row = wm * (BM_ / 2) + mi * 16 + r16;
                af[mi] = *(const short8*)(&As[row * 64 + (co ^ ((row & 7) << 3))]);
            }
            #pragma unroll
            for (int ni = 0; ni < 4; ++ni) {
                int row = wn * 64 + ni * 16 + r16;
                bf[ni] = *(const short8*)(&Bs[row * 64 + (co ^ ((row & 7) << 3))]);
            }
            #pragma unroll
            for (int mi = 0; mi < MF; ++mi)
                #pragma unroll
                for (int ni = 0; ni < 4; ++ni)
                    acc[mi][ni] = __builtin_amdgcn_mfma_f32_16x16x32_bf16(
                        af[mi], bf[ni], acc[mi][ni], 0, 0, 0);
        }
        __syncthreads();
    }
    #pragma unroll
    for (int mi = 0; mi < MF; ++mi) {
        #pragma unroll
        for (int ni = 0; ni < 4; ++ni) {
            int col = bn + wn * 64 + ni * 16 + r16;
            float bv = bias ? bias[col] : 0.f;
            #pragma unroll
            for (int r = 0; r < 4; ++r) {
                int row = bm + wm * (BM_ / 2) + mi * 16 + g * 4 + r;
                float v = acc[mi][ni][r] + bv;
                if (relu) v = fmaxf(v, 0.f);
                if constexpr (OUTBF)
                    ((unsigned short*)Cv)[(size_t)row * N + col] = f2bf(v);
                else
                    ((float*)Cv)[(size_t)row * N + col] = v;
            }
        }
    }
}

// ====== GEMM (N=128, K runtime, A bf16) fused with residual-add + LayerNorm ===
__global__ __launch_bounds__(256) void gemm_ln_kernel(
    const unsigned short* __restrict__ A, const unsigned short* __restrict__ Wt,
    const float* __restrict__ bias, const float* __restrict__ gamma,
    const float* __restrict__ beta, float* __restrict__ x,
    unsigned short* __restrict__ xbf, int K)
{
    __shared__ union UU {
        struct { unsigned short As[64 * 64]; unsigned short Bs[128 * 64]; } st;
        float Cs[64 * 132];
    } u;
    int tid = threadIdx.x;
    int bm = blockIdx.x * 64;
    int wave = tid >> 6, lane = tid & 63;
    int wm = wave >> 1, wn = wave & 1;
    int g = lane >> 4, r16 = lane & 15;

    f32x4 acc[2][4] = {};

    for (int k0 = 0; k0 < K; k0 += 64) {
        #pragma unroll
        for (int p = 0; p < 2; ++p) {
            int c = p * 256 + tid;
            int row = c >> 3, c8 = c & 7;
            u32x4 v = *(const u32x4*)(&A[(size_t)(bm + row) * K + k0 + c8 * 8]);
            *(u32x4*)(&u.st.As[row * 64 + ((c8 * 8) ^ ((row & 7) << 3))]) = v;
        }
        #pragma unroll
        for (int p = 0; p < 4; ++p) {
            int c = p * 256 + tid;
            int n = c >> 3, q = c & 7;
            u32x4 v = *(const u32x4*)(&Wt[(size_t)n * K + k0 + q * 8]);
            *(u32x4*)(&u.st.Bs[n * 64 + ((q * 8) ^ ((n & 7) << 3))]) = v;
        }
        __syncthreads();
        #pragma unroll
        for (int kk = 0; kk < 2; ++kk) {
            short8 af[2], bf[4];
            int co = kk * 32 + g * 8;
            #pragma unroll
            for (int mi = 0; mi < 2; ++mi) {
                int row = wm * 32 + mi * 16 + r16;
                af[mi] = *(const short8*)(&u.st.As[row * 64 + (co ^ ((row & 7) << 3))]);
            }
            #pragma unroll
            for (int ni = 0; ni < 4; ++ni) {
                int row = wn * 64 + ni * 16 + r16;
                bf[ni] = *(const short8*)(&u.st.Bs[row * 64 + (co ^ ((row & 7) << 3))]);
            }
            #pragma unroll
            for (int mi = 0; mi < 2; ++mi)
                #pragma unroll
                for (int ni = 0; ni < 4; ++ni)
                    acc[mi][ni] = __builtin_amdgcn_mfma_f32_16x16x32_bf16(
                        af[mi], bf[ni], acc[mi][ni], 0, 0, 0);
        }
        __syncthreads();
    }
    // C-tile -> LDS (stride 132, conflict-free)
    #pragma unroll
    for (int mi = 0; mi < 2; ++mi) {
        #pragma unroll
        for (int ni = 0; ni < 4; ++ni) {
            int col = wn * 64 + ni * 16 + r16;
            float bv = bias ? bias[col] : 0.f;
            #pragma unroll
            for (int r = 0; r < 4; ++r) {
                int row = wm * 32 + mi * 16 + g * 4 + r;
                u.Cs[row * 132 + col] = acc[mi][ni][r] + bv;
            }
        }
    }
    __syncthreads();
    // residual add + LN, one wave per row, 16 rows/wave
    #pragma unroll 4
    for (int rr = 0; rr < 16; ++rr) {
        int row = wave * 16 + rr;
        size_t go = (size_t)(bm + row) * 128;
        float v0 = u.Cs[row * 132 + lane] + x[go + lane];
        float v1 = u.Cs[row * 132 + 64 + lane] + x[go + 64 + lane];
        float sum = v0 + v1, sq = v0 * v0 + v1 * v1;
        #pragma unroll
        for (int o2 = 32; o2 >= 1; o2 >>= 1) {
            sum += __shfl_xor(sum, o2);
            sq  += __shfl_xor(sq, o2);
        }
        float mu = sum * (1.f / 128.f);
        float var = sq * (1.f / 128.f) - mu * mu;
        float rs = rsqrtf(var + 1e-5f);
        float o0 = (v0 - mu) * rs * gamma[lane] + beta[lane];
        float o1 = (v1 - mu) * rs * gamma[lane + 64] + beta[lane + 64];
        x[go + lane] = o0;
        x[go + 64 + lane] = o1;
        xbf[go + lane] = f2bf(o0);
        xbf[go + 64 + lane] = f2bf(o1);
    }
}

// ================= q_all = time_embed(arange(48)) @ wq  (48 x 64) =============
__global__ __launch_bounds__(256) void compute_q_kernel(
    const float* __restrict__ te_w, const float* __restrict__ te_b,
    const float* __restrict__ wq, float* __restrict__ q_all)
{
    __shared__ float qte[AL_ * DTE_];
    int tid = threadIdx.x;
    for (int idx = tid; idx < AL_ * DTE_; idx += 256) {
        int a = idx >> 6, j = idx & 63;
        float lin = fmaf((float)a, te_w[j], te_b[j]);
        qte[idx] = (j == 0) ? lin : sinf(lin);
    }
    __syncthreads();
    for (int idx = tid; idx < AL_ * DTE_; idx += 256) {
        int a = idx >> 6, j2 = idx & 63;
        float s = 0.f;
        for (int j = 0; j < DTE_; ++j) s = fmaf(qte[a * 64 + j], wq[j * 64 + j2], s);
        q_all[idx] = s;
    }
}

// ================= First (irregular-time) attention, fused per batch ==========
// Conflict-free layouts, wave-parallel softmax, kk row held in registers.
__global__ __launch_bounds__(256) void first_attn_kernel(
    const float* __restrict__ note_times, const int* __restrict__ note_counts,
    const float* __restrict__ te_w, const float* __restrict__ te_b,
    const float* __restrict__ wk, const float* __restrict__ q_all,
    const unsigned short* __restrict__ note_emb, float* __restrict__ x_out,
    unsigned short* __restrict__ xbf_out)
{
    __shared__ union UU {
        struct { float kte[64 * 68]; float kkR[64 * 68]; } p2;
        float nlds[64 * 132];
    } u;
    __shared__ float qs[AL_ * 64];
    __shared__ float abar[AL_ * 64];
    int b = blockIdx.x;
    int tid = threadIdx.x, wave = tid >> 6, lane = tid & 63;
    int nc = note_counts[b];

    // phase 1: kte (padded 68) + qs
    for (int i = tid; i < 64 * 64; i += 256) {
        int l = i >> 6, j = i & 63;
        float t = note_times[b * 64 + l];
        float lin = fmaf(t, te_w[j], te_b[j]);
        u.p2.kte[l * 68 + j] = (j == 0) ? lin : sinf(lin);
    }
    for (int i = tid; i < AL_ * 64; i += 256) qs[i] = q_all[i];
    __syncthreads();

    // phase 2: kk[l][d] with lanes = d (coalesced wk); store row-major pad 68
    for (int it = 0; it < 16; ++it) {
        int l = it * 4 + wave;
        float s = 0.f;
        #pragma unroll
        for (int j4 = 0; j4 < 16; ++j4) {
            f32x4 kt = *(const f32x4*)(&u.p2.kte[l * 68 + j4 * 4]);
            s = fmaf(kt[0], wk[(j4 * 4 + 0) * 64 + lane], s);
            s = fmaf(kt[1], wk[(j4 * 4 + 1) * 64 + lane], s);
            s = fmaf(kt[2], wk[(j4 * 4 + 2) * 64 + lane], s);
            s = fmaf(kt[3], wk[(j4 * 4 + 3) * 64 + lane], s);
        }
        u.p2.kkR[l * 68 + lane] = s;
    }
    __syncthreads();

    // phase 3: lane owns k-row l=lane (held in 16 f32x4 regs); wave-parallel
    // softmax over l; all 8 heads accumulated in-register.
    f32x4 kv[16];
    #pragma unroll
    for (int q = 0; q < 16; ++q) kv[q] = *(const f32x4*)(&u.p2.kkR[lane * 68 + q * 4]);
    const float scale = 0.35355339059327373f; // 1/sqrt(8)
    for (int ai = 0; ai < 12; ++ai) {
        int a = wave * 12 + ai;
        float acc = 0.f;
        #pragma unroll
        for (int h = 0; h < 8; ++h) {
            f32x4 q0 = *(const f32x4*)(&qs[a * 64 + h * 8]);
            f32x4 q1 = *(const f32x4*)(&qs[a * 64 + h * 8 + 4]);
            f32x4 k0 = kv[h * 2], k1 = kv[h * 2 + 1];
            float s = q0[0] * k0[0];
            s = fmaf(q0[1], k0[1], s);
            s = fmaf(q0[2], k0[2], s);
            s = fmaf(q0[3], k0[3], s);
            s = fmaf(q1[0], k1[0], s);
            s = fmaf(q1[1], k1[1], s);
            s = fmaf(q1[2], k1[2], s);
            s = fmaf(q1[3], k1[3], s);
            s = (lane < nc) ? s * scale : -1e9f;
            float m = s;
            #pragma unroll
            for (int o2 = 32; o2 >= 1; o2 >>= 1) m = fmaxf(m, __shfl_xor(m, o2));
            float e = expf(s - m);
            float sum = e;
            #pragma unroll
            for (int o2 = 32; o2 >= 1; o2 >>= 1) sum += __shfl_xor(sum, o2);
            acc = fmaf(e, 0.125f / sum, acc);
        }
        abar[a * 64 + lane] = acc;
    }
    __syncthreads();

    // phase 4: stage note_emb (bf16 -> f32, stride 132), then PV
    for (int i = tid; i < 64 * 16; i += 256) {
        int l = i >> 4, c = i & 15;
        u32x4 v = *(const u32x4*)(&note_emb[((size_t)b * 64 + l) * 128 + c * 8]);
        f32x4 f0, f1;
        f0[0] = bf2f((unsigned short)(v[0] & 0xffff)); f0[1] = bf2f((unsigned short)(v[0] >> 16));
        f0[2] = bf2f((unsigned short)(v[1] & 0xffff)); f0[3] = bf2f((unsigned short)(v[1] >> 16));
        f1[0] = bf2f((unsigned short)(v[2] & 0xffff)); f1[1] = bf2f((unsigned short)(v[2] >> 16));
        f1[2] = bf2f((unsigned short)(v[3] & 0xffff)); f1[3] = bf2f((unsigned short)(v[3] >> 16));
        *(f32x4*)(&u.nlds[l * 132 + c * 8]) = f0;
        *(f32x4*)(&u.nlds[l * 132 + c * 8 + 4]) = f1;
    }
    __syncthreads();
    for (int i = tid; i < AL_ * 32; i += 256) {
        int a = i >> 5, c = i & 31;
        f32x4 av = {0.f, 0.f, 0.f, 0.f};
        for (int l = 0; l < 64; ++l) {
            float w = abar[a * 64 + l];
            f32x4 nv = *(const f32x4*)(&u.nlds[l * 132 + c * 4]);
            av[0] = fmaf(w, nv[0], av[0]);
            av[1] = fmaf(w, nv[1], av[1]);
            av[2] = fmaf(w, nv[2], av[2]);
            av[3] = fmaf(w, nv[3], av[3]);
        }
        if (nc <= 0) { av[0] = av[1] = av[2] = av[3] = 0.f; }
        size_t o = ((size_t)b * AL_ + a) * 128 + c * 4;
        *(f32x4*)(&x_out[o]) = av;
        u32x2 pb;
        pb[0] = f2bf2(av[0], av[1]);
        pb[1] = f2bf2(av[2], av[3]);
        *(u32x2*)(&xbf_out[o]) = pb;
    }
}

// ================= Transformer self-attention: block per (b,h), bf16 io =======
__global__ __launch_bounds__(256) void attn2_kernel(
    const unsigned short* __restrict__ qkv, unsigned short* __restrict__ o)
{
    __shared__ float qh[AL_ * 20], kh[AL_ * 20], vh[AL_ * 20];
    __shared__ float s[AL_ * 49];
    int bid = blockIdx.x;
    int b = bid >> 3, h = bid & 7;
    int tid = threadIdx.x, wave = tid >> 6, lane = tid & 63;
    const unsigned short* base = qkv + (size_t)b * AL_ * 384 + h * 16;
    for (int i = tid; i < 576; i += 256) {
        int mat = i / 192, rem = i - mat * 192;
        int a = rem >> 2, c = rem & 3;
        u32x2 v = *(const u32x2*)(&base[(size_t)a * 384 + mat * 128 + c * 4]);
        float* dst = (mat == 0) ? qh : (mat == 1) ? kh : vh;
        f32x4 f;
        f[0] = bf2f((unsigned short)(v[0] & 0xffff));
        f[1] = bf2f((unsigned short)(v[0] >> 16));
        f[2] = bf2f((unsigned short)(v[1] & 0xffff));
        f[3] = bf2f((unsigned short)(v[1] >> 16));
        *(f32x4*)(&dst[a * 20 + c * 4]) = f;
    }
    __syncthreads();
    for (int i = tid; i < AL_ * AL_; i += 256) {
        int a = i / 48, kx = i - a * 48;
        f32x4 a4 = {0.f, 0.f, 0.f, 0.f};
        #pragma unroll
        for (int c = 0; c < 4; ++c) {
            f32x4 qv = *(const f32x4*)(&qh[a * 20 + c * 4]);
            f32x4 kk = *(const f32x4*)(&kh[kx * 20 + c * 4]);
            a4[0] = fmaf(qv[0], kk[0], a4[0]);
            a4[1] = fmaf(qv[1], kk[1], a4[1]);
            a4[2] = fmaf(qv[2], kk[2], a4[2]);
            a4[3] = fmaf(qv[3], kk[3], a4[3]);
        }
        s[a * 49 + kx] = (a4[0] + a4[1] + a4[2] + a4[3]) * 0.25f;
    }
    __syncthreads();
    for (int ai = 0; ai < 12; ++ai) {
        int a = wave * 12 + ai;
        float v = (lane < 48) ? s[a * 49 + lane] : -3.0e38f;
        float m = v;
        #pragma unroll
        for (int o2 = 32; o2 >= 1; o2 >>= 1) m = fmaxf(m, __shfl_xor(m, o2));
        float e = (lane < 48) ? expf(v - m) : 0.f;
        float sum = e;
        #pragma unroll
        for (int o2 = 32; o2 >= 1; o2 >>= 1) sum += __shfl_xor(sum, o2);
        if (lane < 48) s[a * 49 + lane] = e / sum;
    }
    __syncthreads();
    if (tid < 192) {
        int a = tid >> 2, dq = tid & 3;
        f32x4 a4 = {0.f, 0.f, 0.f, 0.f};
        for (int j = 0; j < 48; ++j) {
            float w = s[a * 49 + j];
            f32x4 vv = *(const f32x4*)(&vh[j * 20 + dq * 4]);
            a4[0] = fmaf(w, vv[0], a4[0]);
            a4[1] = fmaf(w, vv[1], a4[1]);
            a4[2] = fmaf(w, vv[2], a4[2]);
            a4[3] = fmaf(w, vv[3], a4[3]);
        }
        u32x2 pb;
        pb[0] = f2bf2(a4[0], a4[1]);
        pb[1] = f2bf2(a4[2], a4[3]);
        *(u32x2*)(&o[((size_t)b * AL_ + a) * 128 + h * 16 + dq * 4]) = pb;
    }
}

// ================= Classifier head ============================================
__global__ __launch_bounds__(64) void head_kernel(
    const float* __restrict__ x, const float* __restrict__ w1,
    const float* __restrict__ b1, const float* __restrict__ w2,
    const float* __restrict__ b2, float* __restrict__ out)
{
    int b = blockIdx.x;
    int j = threadIdx.x;
    const float* xr = x + ((size_t)b * AL_ + (AL_ - 1)) * DH_;
    float hj = b1[j];
    for (int d = 0; d < DH_; ++d) hj = fmaf(xr[d], w1[d * 64 + j], hj);
    hj = fmaxf(hj, 0.f);
    float acc = hj * w2[j];
    #pragma unroll
    for (int d = 32; d >= 1; d >>= 1) acc += __shfl_xor(acc, d);
    if (j == 0) out[b] = acc + b2[0];
}

// ================= Launch =====================================================
extern "C" void kernel_launch(void* const* d_in, const int* in_sizes, int n_in,
                              void* d_out, int out_size, void* d_ws, size_t ws_size,
                              hipStream_t stream) {
    (void)in_sizes; (void)n_in; (void)out_size; (void)ws_size;
    const float* cls_emb    = (const float*)d_in[0];
    const float* note_times = (const float*)d_in[1];
    const int*   note_counts= (const int*)d_in[2];
    const float* proj_w     = (const float*)d_in[3];
    const float* proj_b     = (const float*)d_in[4];
    const float* te_w       = (const float*)d_in[5];
    const float* te_b       = (const float*)d_in[6];
    const float* wq         = (const float*)d_in[7];
    const float* wk         = (const float*)d_in[8];
    const float* tf_wq      = (const float*)d_in[9];
    const float* tf_wk      = (const float*)d_in[10];
    const float* tf_wv      = (const float*)d_in[11];
    const float* tf_wo      = (const float*)d_in[12];
    const float* tf_ln1_g   = (const float*)d_in[13];
    const float* tf_ln1_b   = (const float*)d_in[14];
    const float* tf_w1      = (const float*)d_in[15];
    const float* tf_b1      = (const float*)d_in[16];
    const float* tf_w2      = (const float*)d_in[17];
    const float* tf_b2      = (const float*)d_in[18];
    const float* tf_ln2_g   = (const float*)d_in[19];
    const float* tf_ln2_b   = (const float*)d_in[20];
    const float* cls_w1     = (const float*)d_in[21];
    const float* cls_b1     = (const float*)d_in[22];
    const float* cls_w2     = (const float*)d_in[23];
    const float* cls_b2     = (const float*)d_in[24];
    float* out = (float*)d_out;
    float* ws = (float*)d_ws;

    // workspace layout (float units)
    unsigned short* note_emb16 = (unsigned short*)(ws + 0);        // 2,097,152 u16 -> 1,048,576 f
    float* x       = ws + 1048576;                                  // 1,572,864 f
    float* q_all   = ws + 2621440;                                  // 3,072 f
    unsigned short* qkv16   = (unsigned short*)(ws + 2624512);      // 4,718,592 u16 -> 2,359,296 f
    unsigned short* obuf16  = (unsigned short*)(ws + 4983808);      // 1,572,864 u16 -> 786,432 f
    unsigned short* hidden16= (unsigned short*)(ws + 5770240);      // 6,291,456 u16 -> 3,145,728 f
    unsigned short* xbf     = (unsigned short*)(ws + 8915968);      // 1,572,864 u16 -> 786,432 f
    unsigned short* wt      = (unsigned short*)(ws + 9702400);      // 688,128 u16

    // ---- weight prep table
    TTab tab;
    int tile = 0, idx = 0;
    auto add = [&](const float* src, int dstOff, int K, int N) {
        tab.e[idx].src = src; tab.e[idx].dstOff = dstOff;
        tab.e[idx].K = K; tab.e[idx].N = N; tab.e[idx].tile0 = tile;
        tile += (K / 64) * (N / 64); ++idx;
    };
    add(proj_w, 0, DT_, DH_);
    int layerBase[NL_];
    for (int i = 0; i < NL_; ++i) {
        int base = 98304 + i * 196608;
        layerBase[i] = base;
        add(tf_wq + (size_t)i * DH_ * DH_, base,           DH_, DH_);
        add(tf_wk + (size_t)i * DH_ * DH_, base + 16384,   DH_, DH_);
        add(tf_wv + (size_t)i * DH_ * DH_, base + 32768,   DH_, DH_);
        add(tf_wo + (size_t)i * DH_ * DH_, base + 49152,   DH_, DH_);
        add(tf_w1 + (size_t)i * DH_ * DFF_, base + 65536,  DH_, DFF_);
        add(tf_w2 + (size_t)i * DFF_ * DH_, base + 131072, DFF_, DH_);
    }
    prep_weights_kernel<<<tile, 256, 0, stream>>>(tab, wt);

    const int Mx = B_ * AL_; // 12288

    // note_emb = bf16(cls_emb @ proj_w + proj_b)
    gemm_bf16_kernel<32, 0, 1><<<dim3((B_ * L_) / 32, 1), 256, 0, stream>>>(
        cls_emb, wt, proj_b, note_emb16, B_ * L_, DH_, DT_, 0);

    compute_q_kernel<<<1, 256, 0, stream>>>(te_w, te_b, wq, q_all);
    first_attn_kernel<<<B_, 256, 0, stream>>>(
        note_times, note_counts, te_w, te_b, wk, q_all, note_emb16, x, xbf);

    for (int i = 0; i < NL_; ++i) {
        int base = layerBase[i];
        // qkv = x @ [wq|wk|wv]  -> bf16
        gemm_bf16_kernel<64, 1, 1><<<dim3(Mx / 64, 3), 256, 0, stream>>>(
            xbf, wt + base, nullptr, qkv16, Mx, 384, DH_, 0);
        attn2_kernel<<<B_ * H_, 256, 0, stream>>>(qkv16, obuf16);
        // x = LN(x + attn_out @ wo)
        gemm_ln_kernel<<<Mx / 64, 256, 0, stream>>>(
            obuf16, wt + base + 49152, nullptr,
            tf_ln1_g + i * DH_, tf_ln1_b + i * DH_, x, xbf, DH_);
        // hidden = bf16(relu(x @ w1 + b1))
        gemm_bf16_kernel<64, 1, 1><<<dim3(Mx / 64, 4), 256, 0, stream>>>(
            xbf, wt + base + 65536, tf_b1 + i * DFF_, hidden16, Mx, DFF_, DH_, 1);
        // x = LN(x + hidden @ w2 + b2)
        gemm_ln_kernel<<<Mx / 64, 256, 0, stream>>>(
            hidden16, wt + base + 131072, tf_b2 + i * DH_,
            tf_ln2_g + i * DH_, tf_ln2_b + i * DH_, x, xbf, DFF_);
    }

    head_kernel<<<B_, 64, 0, stream>>>(x, cls_w1, cls_b1, cls_w2, cls_b2, out);
}

// Round 4
// 269.531 us; speedup vs baseline: 2.6831x; 1.1221x over previous
//
#include <hip/hip_runtime.h>
#include <hip/hip_bf16.h>

// Problem constants
#define B_   256
#define L_   64
#define DT_  768
#define DH_  128
#define AL_  48
#define DTE_ 64
#define H_   8
#define NL_  3
#define DFF_ 512

typedef __attribute__((ext_vector_type(4))) float f32x4;
typedef __attribute__((ext_vector_type(4))) unsigned int u32x4;
typedef __attribute__((ext_vector_type(2))) unsigned int u32x2;
typedef __attribute__((ext_vector_type(8))) short short8;

__device__ inline unsigned short f2bf(float f) {
    union { float f; unsigned u; } v; v.f = f;
    unsigned r = (v.u + 0x7FFFu + ((v.u >> 16) & 1u)) >> 16;
    return (unsigned short)r;
}
__device__ inline unsigned f2bf2(float a, float b) {
    return (unsigned)f2bf(a) | ((unsigned)f2bf(b) << 16);
}
__device__ inline float bf2f(unsigned short u) {
    union { unsigned u; float f; } v; v.u = ((unsigned)u) << 16; return v.f;
}

// ================= Weight prep: fp32 [K][N] -> bf16 Wt [N][K] =================
struct TEnt { const float* src; int dstOff; int K; int N; int tile0; };
struct TTab { TEnt e[19]; };

__global__ __launch_bounds__(256) void prep_weights_kernel(TTab tab, unsigned short* __restrict__ wt)
{
    __shared__ unsigned short lds[64][72];
    int ei = 0;
    #pragma unroll
    for (int j = 1; j < 19; ++j) if ((int)blockIdx.x >= tab.e[j].tile0) ei = j;
    TEnt e = tab.e[ei];
    int t = blockIdx.x - e.tile0;
    int tilesK = e.K >> 6;
    int tk = t % tilesK, tn = t / tilesK;
    int tid = threadIdx.x;
    #pragma unroll
    for (int p = 0; p < 16; ++p) {
        int kk = p * 4 + (tid >> 6);
        int n = tid & 63;
        float v = e.src[(size_t)(tk * 64 + kk) * e.N + tn * 64 + n];
        lds[n][kk] = f2bf(v);
    }
    __syncthreads();
    #pragma unroll
    for (int p = 0; p < 2; ++p) {
        int c = p * 256 + tid;
        int n = c >> 3, q = c & 7;
        u32x4 v = *(const u32x4*)(&lds[n][q * 8]);
        *(u32x4*)(&wt[(size_t)e.dstOff + (size_t)(tn * 64 + n) * e.K + tk * 64 + q * 8]) = v;
    }
}

// ================= bf16 MFMA GEMM: C = A(MxK) @ Wt^T  ========================
template<int BM_, int ABF, int OUTBF>
__global__ __launch_bounds__(256) void gemm_bf16_kernel(
    const void* __restrict__ Av, const unsigned short* __restrict__ Wt,
    const float* __restrict__ bias, void* __restrict__ Cv,
    int M, int N, int K, int relu)
{
    constexpr int MF = BM_ / 32;
    __shared__ unsigned short As[BM_ * 64];
    __shared__ unsigned short Bs[128 * 64];
    int tid = threadIdx.x;
    int bm = blockIdx.x * BM_;
    int bn = blockIdx.y * 128;
    int wave = tid >> 6, lane = tid & 63;
    int wm = wave >> 1, wn = wave & 1;
    int g = lane >> 4, r16 = lane & 15;

    f32x4 acc[MF][4] = {};

    for (int k0 = 0; k0 < K; k0 += 64) {
        if constexpr (ABF) {
            const unsigned short* A = (const unsigned short*)Av;
            #pragma unroll
            for (int p = 0; p < MF; ++p) {
                int c = p * 256 + tid;
                int row = c >> 3, c8 = c & 7;
                u32x4 v = *(const u32x4*)(&A[(size_t)(bm + row) * K + k0 + c8 * 8]);
                *(u32x4*)(&As[row * 64 + ((c8 * 8) ^ ((row & 7) << 3))]) = v;
            }
        } else {
            const float* A = (const float*)Av;
            #pragma unroll
            for (int p = 0; p < BM_ / 16; ++p) {
                int row = p * 16 + (tid >> 4);
                int c4 = tid & 15;
                f32x4 v = *(const f32x4*)(&A[(size_t)(bm + row) * K + k0 + c4 * 4]);
                u32x2 w;
                w[0] = f2bf2(v[0], v[1]);
                w[1] = f2bf2(v[2], v[3]);
                *(u32x2*)(&As[row * 64 + ((c4 * 4) ^ ((row & 7) << 3))]) = w;
            }
        }
        #pragma unroll
        for (int p = 0; p < 4; ++p) {
            int c = p * 256 + tid;
            int n = c >> 3, q = c & 7;
            u32x4 v = *(const u32x4*)(&Wt[(size_t)(bn + n) * K + k0 + q * 8]);
            *(u32x4*)(&Bs[n * 64 + ((q * 8) ^ ((n & 7) << 3))]) = v;
        }
        __syncthreads();
        #pragma unroll
        for (int kk = 0; kk < 2; ++kk) {
            short8 af[MF], bf[4];
            int co = kk * 32 + g * 8;
            #pragma unroll
            for (int mi = 0; mi < MF; ++mi) {
                int row = wm * (BM_ / 2) + mi * 16 + r16;
                af[mi] = *(const short8*)(&As[row * 64 + (co ^ ((row & 7) << 3))]);
            }
            #pragma unroll
            for (int ni = 0; ni < 4; ++ni) {
                int row = wn * 64 + ni * 16 + r16;
                bf[ni] = *(const short8*)(&Bs[row * 64 + (co ^ ((row & 7) << 3))]);
            }
            #pragma unroll
            for (int mi = 0; mi < MF; ++mi)
                #pragma unroll
                for (int ni = 0; ni < 4; ++ni)
                    acc[mi][ni] = __builtin_amdgcn_mfma_f32_16x16x32_bf16(
                        af[mi], bf[ni], acc[mi][ni], 0, 0, 0);
        }
        __syncthreads();
    }
    #pragma unroll
    for (int mi = 0; mi < MF; ++mi) {
        #pragma unroll
        for (int ni = 0; ni < 4; ++ni) {
            int col = bn + wn * 64 + ni * 16 + r16;
            float bv = bias ? bias[col] : 0.f;
            #pragma unroll
            for (int r = 0; r < 4; ++r) {
                int row = bm + wm * (BM_ / 2) + mi * 16 + g * 4 + r;
                float v = acc[mi][ni][r] + bv;
                if (relu) v = fmaxf(v, 0.f);
                if constexpr (OUTBF)
                    ((unsigned short*)Cv)[(size_t)row * N + col] = f2bf(v);
                else
                    ((float*)Cv)[(size_t)row * N + col] = v;
            }
        }
    }
}

// ====== GEMM (N=128, A bf16, BM=32) fused with residual-add + LayerNorm =======
__global__ __launch_bounds__(256) void gemm_ln_kernel(
    const unsigned short* __restrict__ A, const unsigned short* __restrict__ Wt,
    const float* __restrict__ bias, const float* __restrict__ gamma,
    const float* __restrict__ beta, float* __restrict__ x,
    unsigned short* __restrict__ xbf, int K)
{
    __shared__ union UU {
        struct { unsigned short As[32 * 64]; unsigned short Bs[128 * 64]; } st;
        float Cs[32 * 132];
    } u;
    int tid = threadIdx.x;
    int bm = blockIdx.x * 32;
    int wave = tid >> 6, lane = tid & 63;
    int wm = wave >> 1, wn = wave & 1;
    int g = lane >> 4, r16 = lane & 15;

    f32x4 acc[4] = {};

    for (int k0 = 0; k0 < K; k0 += 64) {
        {
            int row = tid >> 3, c8 = tid & 7;
            u32x4 v = *(const u32x4*)(&A[(size_t)(bm + row) * K + k0 + c8 * 8]);
            *(u32x4*)(&u.st.As[row * 64 + ((c8 * 8) ^ ((row & 7) << 3))]) = v;
        }
        #pragma unroll
        for (int p = 0; p < 4; ++p) {
            int c = p * 256 + tid;
            int n = c >> 3, q = c & 7;
            u32x4 v = *(const u32x4*)(&Wt[(size_t)n * K + k0 + q * 8]);
            *(u32x4*)(&u.st.Bs[n * 64 + ((q * 8) ^ ((n & 7) << 3))]) = v;
        }
        __syncthreads();
        #pragma unroll
        for (int kk = 0; kk < 2; ++kk) {
            short8 af, bf[4];
            int co = kk * 32 + g * 8;
            {
                int row = wm * 16 + r16;
                af = *(const short8*)(&u.st.As[row * 64 + (co ^ ((row & 7) << 3))]);
            }
            #pragma unroll
            for (int ni = 0; ni < 4; ++ni) {
                int row = wn * 64 + ni * 16 + r16;
                bf[ni] = *(const short8*)(&u.st.Bs[row * 64 + (co ^ ((row & 7) << 3))]);
            }
            #pragma unroll
            for (int ni = 0; ni < 4; ++ni)
                acc[ni] = __builtin_amdgcn_mfma_f32_16x16x32_bf16(af, bf[ni], acc[ni], 0, 0, 0);
        }
        __syncthreads();
    }
    #pragma unroll
    for (int ni = 0; ni < 4; ++ni) {
        int col = wn * 64 + ni * 16 + r16;
        float bv = bias ? bias[col] : 0.f;
        #pragma unroll
        for (int r = 0; r < 4; ++r) {
            int row = wm * 16 + g * 4 + r;
            u.Cs[row * 132 + col] = acc[ni][r] + bv;
        }
    }
    __syncthreads();
    #pragma unroll 4
    for (int rr = 0; rr < 8; ++rr) {
        int row = wave * 8 + rr;
        size_t go = (size_t)(bm + row) * 128;
        float v0 = u.Cs[row * 132 + lane] + x[go + lane];
        float v1 = u.Cs[row * 132 + 64 + lane] + x[go + 64 + lane];
        float sum = v0 + v1, sq = v0 * v0 + v1 * v1;
        #pragma unroll
        for (int o2 = 32; o2 >= 1; o2 >>= 1) {
            sum += __shfl_xor(sum, o2);
            sq  += __shfl_xor(sq, o2);
        }
        float mu = sum * (1.f / 128.f);
        float var = sq * (1.f / 128.f) - mu * mu;
        float rs = rsqrtf(var + 1e-5f);
        float o0 = (v0 - mu) * rs * gamma[lane] + beta[lane];
        float o1 = (v1 - mu) * rs * gamma[lane + 64] + beta[lane + 64];
        x[go + lane] = o0;
        x[go + 64 + lane] = o1;
        xbf[go + lane] = f2bf(o0);
        xbf[go + 64 + lane] = f2bf(o1);
    }
}

// ================= q_all = time_embed(arange(48)) @ wq  (48 x 64) =============
__global__ __launch_bounds__(256) void compute_q_kernel(
    const float* __restrict__ te_w, const float* __restrict__ te_b,
    const float* __restrict__ wq, float* __restrict__ q_all)
{
    __shared__ float qte[AL_ * DTE_];
    int tid = threadIdx.x;
    for (int idx = tid; idx < AL_ * DTE_; idx += 256) {
        int a = idx >> 6, j = idx & 63;
        float lin = fmaf((float)a, te_w[j], te_b[j]);
        qte[idx] = (j == 0) ? lin : __sinf(lin);
    }
    __syncthreads();
    for (int idx = tid; idx < AL_ * DTE_; idx += 256) {
        int a = idx >> 6, j2 = idx & 63;
        float s0 = 0.f, s1 = 0.f, s2 = 0.f, s3 = 0.f;
        for (int j = 0; j < DTE_; j += 4) {
            s0 = fmaf(qte[a * 64 + j], wq[j * 64 + j2], s0);
            s1 = fmaf(qte[a * 64 + j + 1], wq[(j + 1) * 64 + j2], s1);
            s2 = fmaf(qte[a * 64 + j + 2], wq[(j + 2) * 64 + j2], s2);
            s3 = fmaf(qte[a * 64 + j + 3], wq[(j + 3) * 64 + j2], s3);
        }
        q_all[idx] = (s0 + s1) + (s2 + s3);
    }
}

// ================= First (irregular-time) attention, fused per batch ==========
__global__ __launch_bounds__(256) void first_attn_kernel(
    const float* __restrict__ note_times, const int* __restrict__ note_counts,
    const float* __restrict__ te_w, const float* __restrict__ te_b,
    const float* __restrict__ wk, const float* __restrict__ q_all,
    const unsigned short* __restrict__ note_emb, float* __restrict__ x_out,
    unsigned short* __restrict__ xbf_out)
{
    __shared__ union UU {
        float kte[64 * 68];
        struct { unsigned short As[64 * 64]; unsigned short Bs[128 * 64]; } mm;
    } u;
    __shared__ float kkR[64 * 68];
    __shared__ float qs[AL_ * 64];
    int b = blockIdx.x;
    int tid = threadIdx.x, wave = tid >> 6, lane = tid & 63;
    int nc = note_counts[b];

    // phase 1: kte (padded 68) + qs
    for (int i = tid; i < 64 * 64; i += 256) {
        int l = i >> 6, j = i & 63;
        float t = note_times[b * 64 + l];
        float lin = fmaf(t, te_w[j], te_b[j]);
        u.kte[l * 68 + j] = (j == 0) ? lin : __sinf(lin);
    }
    for (int i = tid; i < AL_ * 64; i += 256) qs[i] = q_all[i];
    // preload wk column (lane = output dim d)
    float wkc[64];
    #pragma unroll
    for (int j = 0; j < 64; ++j) wkc[j] = wk[j * 64 + lane];
    __syncthreads();

    // phase 2: kk[l][d], lane = d, 4-way partial sums
    for (int it = 0; it < 16; ++it) {
        int l = it * 4 + wave;
        float s0 = 0.f, s1 = 0.f, s2 = 0.f, s3 = 0.f;
        #pragma unroll
        for (int j4 = 0; j4 < 16; ++j4) {
            f32x4 kt = *(const f32x4*)(&u.kte[l * 68 + j4 * 4]);
            s0 = fmaf(kt[0], wkc[j4 * 4 + 0], s0);
            s1 = fmaf(kt[1], wkc[j4 * 4 + 1], s1);
            s2 = fmaf(kt[2], wkc[j4 * 4 + 2], s2);
            s3 = fmaf(kt[3], wkc[j4 * 4 + 3], s3);
        }
        kkR[l * 68 + lane] = (s0 + s1) + (s2 + s3);
    }
    __syncthreads();
    // kte region is now dead -> becomes As/Bs

    // zero As pad rows 48..63 (MFMA A rows)
    for (int i = tid; i < 16 * 64; i += 256)
        u.mm.As[(48 + (i >> 6)) * 64 + (i & 63)] = 0;

    // phase 3: lane owns note l = lane; 8-head ILP softmax
    f32x4 kv[16];
    #pragma unroll
    for (int q = 0; q < 16; ++q) kv[q] = *(const f32x4*)(&kkR[lane * 68 + q * 4]);
    const float scale = 0.35355339059327373f; // 1/sqrt(8)
    for (int ai = 0; ai < 12; ++ai) {
        int a = wave * 12 + ai;
        float s[8], m[8], e[8], sm[8];
        #pragma unroll
        for (int h = 0; h < 8; ++h) {
            f32x4 q0 = *(const f32x4*)(&qs[a * 64 + h * 8]);
            f32x4 q1 = *(const f32x4*)(&qs[a * 64 + h * 8 + 4]);
            f32x4 k0 = kv[h * 2], k1 = kv[h * 2 + 1];
            float t0 = q0[0] * k0[0];
            t0 = fmaf(q0[1], k0[1], t0);
            t0 = fmaf(q0[2], k0[2], t0);
            t0 = fmaf(q0[3], k0[3], t0);
            float t1 = q1[0] * k1[0];
            t1 = fmaf(q1[1], k1[1], t1);
            t1 = fmaf(q1[2], k1[2], t1);
            t1 = fmaf(q1[3], k1[3], t1);
            s[h] = (lane < nc) ? (t0 + t1) * scale : -1e9f;
        }
        #pragma unroll
        for (int h = 0; h < 8; ++h) m[h] = s[h];
        #pragma unroll
        for (int o2 = 32; o2 >= 1; o2 >>= 1) {
            #pragma unroll
            for (int h = 0; h < 8; ++h) m[h] = fmaxf(m[h], __shfl_xor(m[h], o2));
        }
        #pragma unroll
        for (int h = 0; h < 8; ++h) { e[h] = __expf(s[h] - m[h]); sm[h] = e[h]; }
        #pragma unroll
        for (int o2 = 32; o2 >= 1; o2 >>= 1) {
            #pragma unroll
            for (int h = 0; h < 8; ++h) sm[h] += __shfl_xor(sm[h], o2);
        }
        float acc = 0.f;
        #pragma unroll
        for (int h = 0; h < 8; ++h) acc = fmaf(e[h], __fdividef(0.125f, sm[h]), acc);
        u.mm.As[a * 64 + (lane ^ ((a & 7) << 3))] = f2bf(acc);
    }

    // stage Bs = note_emb^T (f-major, swizzled)
    #pragma unroll
    for (int p = 0; p < 4; ++p) {
        int l = tid & 63, c = p * 4 + (tid >> 6); // c in 0..15
        u32x4 v = *(const u32x4*)(&note_emb[((size_t)b * 64 + l) * 128 + c * 8]);
        #pragma unroll
        for (int j = 0; j < 8; ++j) {
            unsigned short h16 = (unsigned short)((j & 1) ? (v[j >> 1] >> 16) : (v[j >> 1] & 0xffff));
            int f = c * 8 + j;
            u.mm.Bs[f * 64 + (l ^ ((f & 7) << 3))] = h16;
        }
    }
    __syncthreads();

    // phase 4: PV via MFMA, wave grid 2x2, wave tile 32x64
    int wm = wave >> 1, wn = wave & 1, g = lane >> 4, r16 = lane & 15;
    f32x4 acc[2][4] = {};
    #pragma unroll
    for (int kk = 0; kk < 2; ++kk) {
        short8 af[2], bf[4];
        int co = kk * 32 + g * 8;
        #pragma unroll
        for (int mi = 0; mi < 2; ++mi) {
            int row = wm * 32 + mi * 16 + r16;
            af[mi] = *(const short8*)(&u.mm.As[row * 64 + (co ^ ((row & 7) << 3))]);
        }
        #pragma unroll
        for (int ni = 0; ni < 4; ++ni) {
            int row = wn * 64 + ni * 16 + r16;
            bf[ni] = *(const short8*)(&u.mm.Bs[row * 64 + (co ^ ((row & 7) << 3))]);
        }
        #pragma unroll
        for (int mi = 0; mi < 2; ++mi)
            #pragma unroll
            for (int ni = 0; ni < 4; ++ni)
                acc[mi][ni] = __builtin_amdgcn_mfma_f32_16x16x32_bf16(
                    af[mi], bf[ni], acc[mi][ni], 0, 0, 0);
    }
    #pragma unroll
    for (int mi = 0; mi < 2; ++mi) {
        #pragma unroll
        for (int ni = 0; ni < 4; ++ni) {
            int f = wn * 64 + ni * 16 + r16;
            #pragma unroll
            for (int r = 0; r < 4; ++r) {
                int arow = wm * 32 + mi * 16 + g * 4 + r;
                if (arow < AL_) {
                    float v = (nc > 0) ? acc[mi][ni][r] : 0.f;
                    size_t o = ((size_t)b * AL_ + arow) * 128 + f;
                    x_out[o] = v;
                    xbf_out[o] = f2bf(v);
                }
            }
        }
    }
}

// ====== Transformer self-attention per (b,h): fused qkv-proj (MFMA) + attn ====
__global__ __launch_bounds__(256) void attn2_kernel(
    const unsigned short* __restrict__ xbf, const unsigned short* __restrict__ WtL,
    unsigned short* __restrict__ o)
{
    __shared__ unsigned short Xs[AL_ * 128];
    __shared__ float qh[AL_ * 20], kh[AL_ * 20], vh[AL_ * 20];
    __shared__ float s[AL_ * 49];
    int bid = blockIdx.x;
    int b = bid >> 3, h = bid & 7;
    int tid = threadIdx.x, wave = tid >> 6, lane = tid & 63;
    int g = lane >> 4, r16 = lane & 15;

    // stage x[b] (48x128 bf16, swizzled per 64-col chunk)
    #pragma unroll
    for (int p = 0; p < 3; ++p) {
        int i = p * 256 + tid;           // 0..767
        int a = i >> 4, c = (i & 15) * 8;
        u32x4 v = *(const u32x4*)(&xbf[((size_t)b * AL_ + a) * 128 + c]);
        *(u32x4*)(&Xs[a * 128 + (c & 64) + ((c & 63) ^ ((a & 7) << 3))]) = v;
    }
    __syncthreads();

    // waves 0..2 compute q/k/v head slices via MFMA (M=48, N=16, K=128)
    if (wave < 3) {
        f32x4 acc[3] = {};
        const unsigned short* Wm = WtL + wave * 16384 + (size_t)(h * 16) * 128;
        #pragma unroll
        for (int kq = 0; kq < 4; ++kq) {
            short8 bf = *(const short8*)(&Wm[(size_t)r16 * 128 + kq * 32 + g * 8]);
            #pragma unroll
            for (int mi = 0; mi < 3; ++mi) {
                int row = mi * 16 + r16;
                int c = kq * 32 + g * 8;
                short8 af = *(const short8*)(&Xs[row * 128 + (c & 64) + ((c & 63) ^ ((row & 7) << 3))]);
                acc[mi] = __builtin_amdgcn_mfma_f32_16x16x32_bf16(af, bf, acc[mi], 0, 0, 0);
            }
        }
        float* dst = (wave == 0) ? qh : (wave == 1) ? kh : vh;
        #pragma unroll
        for (int mi = 0; mi < 3; ++mi)
            #pragma unroll
            for (int r = 0; r < 4; ++r)
                dst[(mi * 16 + g * 4 + r) * 20 + r16] = acc[mi][r];
    }
    __syncthreads();

    // scores
    for (int i = tid; i < AL_ * AL_; i += 256) {
        int a = i / 48, kx = i - a * 48;
        f32x4 a4 = {0.f, 0.f, 0.f, 0.f};
        #pragma unroll
        for (int c = 0; c < 4; ++c) {
            f32x4 qv = *(const f32x4*)(&qh[a * 20 + c * 4]);
            f32x4 kk = *(const f32x4*)(&kh[kx * 20 + c * 4]);
            a4[0] = fmaf(qv[0], kk[0], a4[0]);
            a4[1] = fmaf(qv[1], kk[1], a4[1]);
            a4[2] = fmaf(qv[2], kk[2], a4[2]);
            a4[3] = fmaf(qv[3], kk[3], a4[3]);
        }
        s[a * 49 + kx] = (a4[0] + a4[1] + a4[2] + a4[3]) * 0.25f;
    }
    __syncthreads();
    for (int ai = 0; ai < 12; ++ai) {
        int a = wave * 12 + ai;
        float v = (lane < 48) ? s[a * 49 + lane] : -3.0e38f;
        float m = v;
        #pragma unroll
        for (int o2 = 32; o2 >= 1; o2 >>= 1) m = fmaxf(m, __shfl_xor(m, o2));
        float e = (lane < 48) ? __expf(v - m) : 0.f;
        float sum = e;
        #pragma unroll
        for (int o2 = 32; o2 >= 1; o2 >>= 1) sum += __shfl_xor(sum, o2);
        if (lane < 48) s[a * 49 + lane] = e * __fdividef(1.f, sum);
    }
    __syncthreads();
    if (tid < 192) {
        int a = tid >> 2, dq = tid & 3;
        f32x4 a4 = {0.f, 0.f, 0.f, 0.f};
        for (int j = 0; j < 48; ++j) {
            float w = s[a * 49 + j];
            f32x4 vv = *(const f32x4*)(&vh[j * 20 + dq * 4]);
            a4[0] = fmaf(w, vv[0], a4[0]);
            a4[1] = fmaf(w, vv[1], a4[1]);
            a4[2] = fmaf(w, vv[2], a4[2]);
            a4[3] = fmaf(w, vv[3], a4[3]);
        }
        u32x2 pb;
        pb[0] = f2bf2(a4[0], a4[1]);
        pb[1] = f2bf2(a4[2], a4[3]);
        *(u32x2*)(&o[((size_t)b * AL_ + a) * 128 + h * 16 + dq * 4]) = pb;
    }
}

// ================= Classifier head ============================================
__global__ __launch_bounds__(64) void head_kernel(
    const float* __restrict__ x, const float* __restrict__ w1,
    const float* __restrict__ b1, const float* __restrict__ w2,
    const float* __restrict__ b2, float* __restrict__ out)
{
    int b = blockIdx.x;
    int j = threadIdx.x;
    const float* xr = x + ((size_t)b * AL_ + (AL_ - 1)) * DH_;
    float hj = b1[j];
    for (int d = 0; d < DH_; ++d) hj = fmaf(xr[d], w1[d * 64 + j], hj);
    hj = fmaxf(hj, 0.f);
    float acc = hj * w2[j];
    #pragma unroll
    for (int d = 32; d >= 1; d >>= 1) acc += __shfl_xor(acc, d);
    if (j == 0) out[b] = acc + b2[0];
}

// ================= Launch =====================================================
extern "C" void kernel_launch(void* const* d_in, const int* in_sizes, int n_in,
                              void* d_out, int out_size, void* d_ws, size_t ws_size,
                              hipStream_t stream) {
    (void)in_sizes; (void)n_in; (void)out_size; (void)ws_size;
    const float* cls_emb    = (const float*)d_in[0];
    const float* note_times = (const float*)d_in[1];
    const int*   note_counts= (const int*)d_in[2];
    const float* proj_w     = (const float*)d_in[3];
    const float* proj_b     = (const float*)d_in[4];
    const float* te_w       = (const float*)d_in[5];
    const float* te_b       = (const float*)d_in[6];
    const float* wq         = (const float*)d_in[7];
    const float* wk         = (const float*)d_in[8];
    const float* tf_wq      = (const float*)d_in[9];
    const float* tf_wk      = (const float*)d_in[10];
    const float* tf_wv      = (const float*)d_in[11];
    const float* tf_wo      = (const float*)d_in[12];
    const float* tf_ln1_g   = (const float*)d_in[13];
    const float* tf_ln1_b   = (const float*)d_in[14];
    const float* tf_w1      = (const float*)d_in[15];
    const float* tf_b1      = (const float*)d_in[16];
    const float* tf_w2      = (const float*)d_in[17];
    const float* tf_b2      = (const float*)d_in[18];
    const float* tf_ln2_g   = (const float*)d_in[19];
    const float* tf_ln2_b   = (const float*)d_in[20];
    const float* cls_w1     = (const float*)d_in[21];
    const float* cls_b1     = (const float*)d_in[22];
    const float* cls_w2     = (const float*)d_in[23];
    const float* cls_b2     = (const float*)d_in[24];
    float* out = (float*)d_out;
    float* ws = (float*)d_ws;

    // workspace layout (float units)
    unsigned short* note_emb16 = (unsigned short*)(ws + 0);      // 1,048,576 f
    float* x        = ws + 1048576;                               // 1,572,864 f
    float* q_all    = ws + 2621440;                               // 3,072 f
    unsigned short* obuf16   = (unsigned short*)(ws + 2624512);   // 786,432 f
    unsigned short* hidden16 = (unsigned short*)(ws + 3410944);   // 3,145,728 f
    unsigned short* xbf      = (unsigned short*)(ws + 6556672);   // 786,432 f
    unsigned short* wt       = (unsigned short*)(ws + 7343104);   // 344,064 f

    // ---- weight prep table
    TTab tab;
    int tile = 0, idx = 0;
    auto add = [&](const float* src, int dstOff, int K, int N) {
        tab.e[idx].src = src; tab.e[idx].dstOff = dstOff;
        tab.e[idx].K = K; tab.e[idx].N = N; tab.e[idx].tile0 = tile;
        tile += (K / 64) * (N / 64); ++idx;
    };
    add(proj_w, 0, DT_, DH_);
    int layerBase[NL_];
    for (int i = 0; i < NL_; ++i) {
        int base = 98304 + i * 196608;
        layerBase[i] = base;
        add(tf_wq + (size_t)i * DH_ * DH_, base,           DH_, DH_);
        add(tf_wk + (size_t)i * DH_ * DH_, base + 16384,   DH_, DH_);
        add(tf_wv + (size_t)i * DH_ * DH_, base + 32768,   DH_, DH_);
        add(tf_wo + (size_t)i * DH_ * DH_, base + 49152,   DH_, DH_);
        add(tf_w1 + (size_t)i * DH_ * DFF_, base + 65536,  DH_, DFF_);
        add(tf_w2 + (size_t)i * DFF_ * DH_, base + 131072, DFF_, DH_);
    }
    prep_weights_kernel<<<tile, 256, 0, stream>>>(tab, wt);

    const int Mx = B_ * AL_; // 12288

    // note_emb = bf16(cls_emb @ proj_w + proj_b)
    gemm_bf16_kernel<32, 0, 1><<<dim3((B_ * L_) / 32, 1), 256, 0, stream>>>(
        cls_emb, wt, proj_b, note_emb16, B_ * L_, DH_, DT_, 0);

    compute_q_kernel<<<1, 256, 0, stream>>>(te_w, te_b, wq, q_all);
    first_attn_kernel<<<B_, 256, 0, stream>>>(
        note_times, note_counts, te_w, te_b, wk, q_all, note_emb16, x, xbf);

    for (int i = 0; i < NL_; ++i) {
        int base = layerBase[i];
        // attention with fused qkv projection
        attn2_kernel<<<B_ * H_, 256, 0, stream>>>(xbf, wt + base, obuf16);
        // x = LN(x + attn_out @ wo)
        gemm_ln_kernel<<<Mx / 32, 256, 0, stream>>>(
            obuf16, wt + base + 49152, nullptr,
            tf_ln1_g + i * DH_, tf_ln1_b + i * DH_, x, xbf, DH_);
        // hidden = bf16(relu(x @ w1 + b1))
        gemm_bf16_kernel<64, 1, 1><<<dim3(Mx / 64, 4), 256, 0, stream>>>(
            xbf, wt + base + 65536, tf_b1 + i * DFF_, hidden16, Mx, DFF_, DH_, 1);
        // x = LN(x + hidden @ w2 + b2)
        gemm_ln_kernel<<<Mx / 32, 256, 0, stream>>>(
            hidden16, wt + base + 131072, tf_b2 + i * DH_,
            tf_ln2_g + i * DH_, tf_ln2_b + i * DH_, x, xbf, DFF_);
    }

    head_kernel<<<B_, 64, 0, stream>>>(x, cls_w1, cls_b1, cls_w2, cls_b2, out);
}